// Round 3
// baseline (459.947 us; speedup 1.0000x reference)
//
#include <hip/hip_runtime.h>

// ---------------------------------------------------------------------------
// Drug-path-only GNN (gene path is dead code w.r.t. outputs).
// Round 3: CSR build partitioned 8-way by node range (mapped to XCDs via
// blockIdx&7) so cursor atomics + csr writes stay XCD-local (round-2 profile:
// 92MB HBM writes for a 6MB buffer = cross-XCD partial-line thrash).
// Also: fused per-layer GEMM pairs, fused pos+neg scorer.
// ---------------------------------------------------------------------------

#define NPART 8

// out_a = A@Wa, out_b = A@Wb ; blockDim = (KOUT, 256/KOUT)
template<int KIN, int KOUT>
__global__ __launch_bounds__(256) void gemm2_kernel(const float* __restrict__ A,
                                                    const float* __restrict__ Wa,
                                                    const float* __restrict__ Wb,
                                                    float* __restrict__ out_a,
                                                    float* __restrict__ out_b, int M) {
    __shared__ float Wsa[KIN * KOUT];
    __shared__ float Wsb[KIN * KOUT];
    const int tid = threadIdx.y * KOUT + threadIdx.x;
    for (int i = tid; i < KIN * KOUT; i += 256) { Wsa[i] = Wa[i]; Wsb[i] = Wb[i]; }
    __syncthreads();
    const int n = threadIdx.x;
    const int ROWS = 256 / KOUT;
    for (int m = blockIdx.x * ROWS + threadIdx.y; m < M; m += gridDim.x * ROWS) {
        const float* a = A + (size_t)m * KIN;
        float aa = 0.0f, ab = 0.0f;
#pragma unroll
        for (int k = 0; k < KIN; ++k) {
            const float av = a[k];
            aa = fmaf(av, Wsa[k * KOUT + n], aa);
            ab = fmaf(av, Wsb[k * KOUT + n], ab);
        }
        out_a[(size_t)m * KOUT + n] = aa;
        out_b[(size_t)m * KOUT + n] = ab;
    }
}

// 8-way node-range-partitioned degree histogram; partition = blockIdx & 7.
__global__ __launch_bounds__(256) void degree_part_kernel(const int* __restrict__ dst,
                                                          int* __restrict__ deg,
                                                          int E, int psz) {
    const int part = blockIdx.x & (NPART - 1);
    const int lo = part * psz, hi = lo + psz;
    const int bpp = gridDim.x >> 3;         // blocks per partition
    const int bip = blockIdx.x >> 3;
    const int stride = bpp * 256;
    for (int e = bip * 256 + threadIdx.x; e < E; e += stride) {
        const int d = dst[e];
        if (d >= lo && d < hi) atomicAdd(&deg[d], 1);
    }
}

// single-block exclusive scan; writes off[0..N] and cursor[i]=off[i]
__global__ __launch_bounds__(1024) void scan_kernel(const int* __restrict__ deg,
                                                    int* __restrict__ off,
                                                    int* __restrict__ cursor, int N) {
    __shared__ int part[1024];
    const int t = threadIdx.x;
    const int per = (N + 1023) / 1024;
    const int beg = t * per;
    const int end = min(beg + per, N);
    int s = 0;
    for (int i = beg; i < end; ++i) s += deg[i];
    part[t] = s;
    __syncthreads();
    for (int d = 1; d < 1024; d <<= 1) {
        int v = (t >= d) ? part[t - d] : 0;
        __syncthreads();
        part[t] += v;
        __syncthreads();
    }
    int run = (t == 0) ? 0 : part[t - 1];
    for (int i = beg; i < end; ++i) { off[i] = run; cursor[i] = run; run += deg[i]; }
    if (t == 1023) off[N] = part[1023];
}

// 8-way partitioned bucket fill; after completion cursor[n] == segment end.
__global__ __launch_bounds__(256) void fill_part_kernel(const int* __restrict__ src,
                                                        const int* __restrict__ dst,
                                                        int* __restrict__ cursor,
                                                        int* __restrict__ csr_src,
                                                        int E, int psz) {
    const int part = blockIdx.x & (NPART - 1);
    const int lo = part * psz, hi = lo + psz;
    const int bpp = gridDim.x >> 3;
    const int bip = blockIdx.x >> 3;
    const int stride = bpp * 256;
    for (int e = bip * 256 + threadIdx.x; e < E; e += stride) {
        const int d = dst[e];
        const int s = src[e];
        if (d >= lo && d < hi) {
            const int p = atomicAdd(&cursor[d], 1);
            csr_src[p] = s;
        }
    }
}

// One W-lane group per dst node: register-accumulate, fused mean+self+bias(+relu)
template<int W, bool RELU>
__global__ __launch_bounds__(256) void gather_combine_kernel(
        const float* __restrict__ msg, const int* __restrict__ csr_src,
        const int* __restrict__ off, const int* __restrict__ endp,
        const float* __restrict__ selfb, const float* __restrict__ b,
        float* __restrict__ out, int N) {
    const int GRP = 256 / W;
    const int g = threadIdx.x / W;
    const int lane = threadIdx.x % W;
    const float bk = b[lane];
    for (int n = blockIdx.x * GRP + g; n < N; n += gridDim.x * GRP) {
        const int beg = off[n], end = endp[n];
        float acc = 0.0f;
        int i = beg;
        for (; i + 4 <= end; i += 4) {
            const int s0 = csr_src[i], s1 = csr_src[i + 1];
            const int s2 = csr_src[i + 2], s3 = csr_src[i + 3];
            const float v0 = msg[(size_t)s0 * W + lane];
            const float v1 = msg[(size_t)s1 * W + lane];
            const float v2 = msg[(size_t)s2 * W + lane];
            const float v3 = msg[(size_t)s3 * W + lane];
            acc += (v0 + v1) + (v2 + v3);
        }
        for (; i < end; ++i) acc += msg[(size_t)csr_src[i] * W + lane];
        const float d = (end > beg) ? (float)(end - beg) : 1.0f;
        float v = acc / d + selfb[(size_t)n * W + lane] + bk;
        if (RELU) v = fmaxf(v, 0.0f);
        out[(size_t)n * W + lane] = v;
    }
}

// fused pos+neg scorer: 8 lanes per edge, float4 slices of 32-wide h rows
__global__ __launch_bounds__(256) void score2_kernel(const float* __restrict__ h,
                                                     const int* __restrict__ sA,
                                                     const int* __restrict__ dA,
                                                     const int* __restrict__ sB,
                                                     const int* __restrict__ dB,
                                                     const float* __restrict__ wrel,
                                                     float* __restrict__ outA,
                                                     float* __restrict__ outB,
                                                     int EA, int EB) {
    const int lj = threadIdx.x & 7;
    const size_t grp = ((size_t)blockIdx.x * blockDim.x + threadIdx.x) >> 3;
    const size_t ngrp = ((size_t)gridDim.x * blockDim.x) >> 3;
    const float4 w = *(const float4*)(wrel + lj * 4);
    const size_t total = (size_t)EA + (size_t)EB;
    for (size_t e = grp; e < total; e += ngrp) {
        int s, d; float* o;
        if (e < (size_t)EA) { s = sA[e]; d = dA[e]; o = outA + e; }
        else { const size_t e2 = e - EA; s = sB[e2]; d = dB[e2]; o = outB + e2; }
        const float4 hs = *(const float4*)(h + (size_t)s * 32 + lj * 4);
        const float4 hd = *(const float4*)(h + (size_t)d * 32 + lj * 4);
        float p = hs.x * w.x * hd.x + hs.y * w.y * hd.y +
                  hs.z * w.z * hd.z + hs.w * w.w * hd.w;
        p += __shfl_xor(p, 1, 64);
        p += __shfl_xor(p, 2, 64);
        p += __shfl_xor(p, 4, 64);
        if (lj == 0) *o = p;
    }
}

extern "C" void kernel_launch(void* const* d_in, const int* in_sizes, int n_in,
                              void* d_out, int out_size, void* d_ws, size_t ws_size,
                              hipStream_t stream) {
    const float* feat_drug    = (const float*)d_in[0];
    const int*   dd_src       = (const int*)d_in[2];
    const int*   dd_dst       = (const int*)d_in[3];
    const int*   neg_src      = (const int*)d_in[8];
    const int*   neg_dst      = (const int*)d_in[9];
    const float* W1_dd        = (const float*)d_in[10];
    const float* W1_self_drug = (const float*)d_in[13];
    const float* b1           = (const float*)d_in[15];
    const float* W2_dd        = (const float*)d_in[16];
    const float* W2_self_drug = (const float*)d_in[19];
    const float* b2           = (const float*)d_in[21];
    const float* w_rel        = (const float*)d_in[22];

    const int N  = in_sizes[0] / 128;  // 20000 drugs
    const int E  = in_sizes[2];        // 1.5M dd edges
    const int EN = in_sizes[8];        // 1.5M neg edges
    const int PSZ = (N + NPART - 1) / NPART;

    // workspace layout (4-byte elements)
    char* ws = (char*)d_ws;
    int*   deg_i   = (int*)ws;                         ws += (size_t)N * 4;
    int*   off     = (int*)ws;                         ws += (size_t)(N + 1) * 4;
    int*   cursor  = (int*)ws;                         ws += (size_t)(N + 1) * 4;
    int*   csr_src = (int*)ws;                         ws += (size_t)E * 4;
    float* msg1    = (float*)ws;                       ws += (size_t)N * 64 * 4;
    float* self1   = (float*)ws;                       ws += (size_t)N * 64 * 4;
    float* h1      = (float*)ws;                       ws += (size_t)N * 64 * 4;
    float* msg2    = (float*)ws;                       ws += (size_t)N * 32 * 4;
    float* self2   = (float*)ws;                       ws += (size_t)N * 32 * 4;
    float* h2      = (float*)ws;                       ws += (size_t)N * 32 * 4;

    float* pos = (float*)d_out;
    float* neg = pos + E;

    hipMemsetAsync(deg_i, 0, (size_t)N * sizeof(int), stream);

    // ---- CSR-by-dst build (XCD-partitioned) ----
    degree_part_kernel<<<512, 256, 0, stream>>>(dd_dst, deg_i, E, PSZ);
    scan_kernel<<<1, 1024, 0, stream>>>(deg_i, off, cursor, N);
    fill_part_kernel<<<512, 256, 0, stream>>>(dd_src, dd_dst, cursor, csr_src, E, PSZ);

    // ---- layer 1 ----
    gemm2_kernel<128, 64><<<(N + 3) / 4, dim3(64, 4), 0, stream>>>(
        feat_drug, W1_dd, W1_self_drug, msg1, self1, N);
    gather_combine_kernel<64, true><<<(N + 3) / 4, 256, 0, stream>>>(
        msg1, csr_src, off, cursor, self1, b1, h1, N);

    // ---- layer 2 ----
    gemm2_kernel<64, 32><<<(N + 7) / 8, dim3(32, 8), 0, stream>>>(
        h1, W2_dd, W2_self_drug, msg2, self2, N);
    gather_combine_kernel<32, false><<<(N + 7) / 8, 256, 0, stream>>>(
        msg2, csr_src, off, cursor, self2, b2, h2, N);

    // ---- scorer (pos + neg fused) ----
    score2_kernel<<<4096, 256, 0, stream>>>(h2, dd_src, dd_dst, neg_src, neg_dst,
                                            w_rel, pos, neg, E, EN);
}

// Round 4
// 431.084 us; speedup vs baseline: 1.0670x; 1.0670x over previous
//
#include <hip/hip_runtime.h>

// ---------------------------------------------------------------------------
// Drug-path-only GNN (gene path is dead code w.r.t. outputs).
// Round 4: persistent-block GEMMs. Round-3 profile showed gemm2<128,64> at
// 133us with 10% occupancy: 5000 blocks x ONE 4-row iter each = 64KB LDS
// weight fill per 4 rows. Grid=512 (2 blocks/CU) amortizes the fill ~40x.
// ---------------------------------------------------------------------------

#define NPART 8

// out_a = A@Wa, out_b = A@Wb ; blockDim = (KOUT, 256/KOUT); persistent grid
template<int KIN, int KOUT>
__global__ __launch_bounds__(256) void gemm2_kernel(const float* __restrict__ A,
                                                    const float* __restrict__ Wa,
                                                    const float* __restrict__ Wb,
                                                    float* __restrict__ out_a,
                                                    float* __restrict__ out_b, int M) {
    __shared__ float Wsa[KIN * KOUT];
    __shared__ float Wsb[KIN * KOUT];
    const int tid = threadIdx.y * KOUT + threadIdx.x;
    for (int i = tid; i < KIN * KOUT; i += 256) { Wsa[i] = Wa[i]; Wsb[i] = Wb[i]; }
    __syncthreads();
    const int n = threadIdx.x;
    const int ROWS = 256 / KOUT;
    for (int m = blockIdx.x * ROWS + threadIdx.y; m < M; m += gridDim.x * ROWS) {
        const float* a = A + (size_t)m * KIN;
        float aa = 0.0f, ab = 0.0f;
#pragma unroll
        for (int k = 0; k < KIN; ++k) {
            const float av = a[k];
            aa = fmaf(av, Wsa[k * KOUT + n], aa);
            ab = fmaf(av, Wsb[k * KOUT + n], ab);
        }
        out_a[(size_t)m * KOUT + n] = aa;
        out_b[(size_t)m * KOUT + n] = ab;
    }
}

// 8-way node-range-partitioned degree histogram; partition = blockIdx & 7.
__global__ __launch_bounds__(256) void degree_part_kernel(const int* __restrict__ dst,
                                                          int* __restrict__ deg,
                                                          int E, int psz) {
    const int part = blockIdx.x & (NPART - 1);
    const int lo = part * psz, hi = lo + psz;
    const int bpp = gridDim.x >> 3;
    const int bip = blockIdx.x >> 3;
    const int stride = bpp * 256;
    for (int e = bip * 256 + threadIdx.x; e < E; e += stride) {
        const int d = dst[e];
        if (d >= lo && d < hi) atomicAdd(&deg[d], 1);
    }
}

// single-block exclusive scan; writes off[0..N] and cursor[i]=off[i]
__global__ __launch_bounds__(1024) void scan_kernel(const int* __restrict__ deg,
                                                    int* __restrict__ off,
                                                    int* __restrict__ cursor, int N) {
    __shared__ int part[1024];
    const int t = threadIdx.x;
    const int per = (N + 1023) / 1024;
    const int beg = t * per;
    const int end = min(beg + per, N);
    int s = 0;
    for (int i = beg; i < end; ++i) s += deg[i];
    part[t] = s;
    __syncthreads();
    for (int d = 1; d < 1024; d <<= 1) {
        int v = (t >= d) ? part[t - d] : 0;
        __syncthreads();
        part[t] += v;
        __syncthreads();
    }
    int run = (t == 0) ? 0 : part[t - 1];
    for (int i = beg; i < end; ++i) { off[i] = run; cursor[i] = run; run += deg[i]; }
    if (t == 1023) off[N] = part[1023];
}

// 8-way partitioned bucket fill; after completion cursor[n] == segment end.
__global__ __launch_bounds__(256) void fill_part_kernel(const int* __restrict__ src,
                                                        const int* __restrict__ dst,
                                                        int* __restrict__ cursor,
                                                        int* __restrict__ csr_src,
                                                        int E, int psz) {
    const int part = blockIdx.x & (NPART - 1);
    const int lo = part * psz, hi = lo + psz;
    const int bpp = gridDim.x >> 3;
    const int bip = blockIdx.x >> 3;
    const int stride = bpp * 256;
    for (int e = bip * 256 + threadIdx.x; e < E; e += stride) {
        const int d = dst[e];
        const int s = src[e];
        if (d >= lo && d < hi) {
            const int p = atomicAdd(&cursor[d], 1);
            csr_src[p] = s;
        }
    }
}

// One W-lane group per dst node: register-accumulate, fused mean+self+bias(+relu)
template<int W, bool RELU>
__global__ __launch_bounds__(256) void gather_combine_kernel(
        const float* __restrict__ msg, const int* __restrict__ csr_src,
        const int* __restrict__ off, const int* __restrict__ endp,
        const float* __restrict__ selfb, const float* __restrict__ b,
        float* __restrict__ out, int N) {
    const int GRP = 256 / W;
    const int g = threadIdx.x / W;
    const int lane = threadIdx.x % W;
    const float bk = b[lane];
    for (int n = blockIdx.x * GRP + g; n < N; n += gridDim.x * GRP) {
        const int beg = off[n], end = endp[n];
        float acc = 0.0f;
        int i = beg;
        for (; i + 4 <= end; i += 4) {
            const int s0 = csr_src[i], s1 = csr_src[i + 1];
            const int s2 = csr_src[i + 2], s3 = csr_src[i + 3];
            const float v0 = msg[(size_t)s0 * W + lane];
            const float v1 = msg[(size_t)s1 * W + lane];
            const float v2 = msg[(size_t)s2 * W + lane];
            const float v3 = msg[(size_t)s3 * W + lane];
            acc += (v0 + v1) + (v2 + v3);
        }
        for (; i < end; ++i) acc += msg[(size_t)csr_src[i] * W + lane];
        const float d = (end > beg) ? (float)(end - beg) : 1.0f;
        float v = acc / d + selfb[(size_t)n * W + lane] + bk;
        if (RELU) v = fmaxf(v, 0.0f);
        out[(size_t)n * W + lane] = v;
    }
}

// fused pos+neg scorer: 8 lanes per edge, float4 slices of 32-wide h rows
__global__ __launch_bounds__(256) void score2_kernel(const float* __restrict__ h,
                                                     const int* __restrict__ sA,
                                                     const int* __restrict__ dA,
                                                     const int* __restrict__ sB,
                                                     const int* __restrict__ dB,
                                                     const float* __restrict__ wrel,
                                                     float* __restrict__ outA,
                                                     float* __restrict__ outB,
                                                     int EA, int EB) {
    const int lj = threadIdx.x & 7;
    const size_t grp = ((size_t)blockIdx.x * blockDim.x + threadIdx.x) >> 3;
    const size_t ngrp = ((size_t)gridDim.x * blockDim.x) >> 3;
    const float4 w = *(const float4*)(wrel + lj * 4);
    const size_t total = (size_t)EA + (size_t)EB;
    for (size_t e = grp; e < total; e += ngrp) {
        int s, d; float* o;
        if (e < (size_t)EA) { s = sA[e]; d = dA[e]; o = outA + e; }
        else { const size_t e2 = e - EA; s = sB[e2]; d = dB[e2]; o = outB + e2; }
        const float4 hs = *(const float4*)(h + (size_t)s * 32 + lj * 4);
        const float4 hd = *(const float4*)(h + (size_t)d * 32 + lj * 4);
        float p = hs.x * w.x * hd.x + hs.y * w.y * hd.y +
                  hs.z * w.z * hd.z + hs.w * w.w * hd.w;
        p += __shfl_xor(p, 1, 64);
        p += __shfl_xor(p, 2, 64);
        p += __shfl_xor(p, 4, 64);
        if (lj == 0) *o = p;
    }
}

extern "C" void kernel_launch(void* const* d_in, const int* in_sizes, int n_in,
                              void* d_out, int out_size, void* d_ws, size_t ws_size,
                              hipStream_t stream) {
    const float* feat_drug    = (const float*)d_in[0];
    const int*   dd_src       = (const int*)d_in[2];
    const int*   dd_dst       = (const int*)d_in[3];
    const int*   neg_src      = (const int*)d_in[8];
    const int*   neg_dst      = (const int*)d_in[9];
    const float* W1_dd        = (const float*)d_in[10];
    const float* W1_self_drug = (const float*)d_in[13];
    const float* b1           = (const float*)d_in[15];
    const float* W2_dd        = (const float*)d_in[16];
    const float* W2_self_drug = (const float*)d_in[19];
    const float* b2           = (const float*)d_in[21];
    const float* w_rel        = (const float*)d_in[22];

    const int N  = in_sizes[0] / 128;  // 20000 drugs
    const int E  = in_sizes[2];        // 1.5M dd edges
    const int EN = in_sizes[8];        // 1.5M neg edges
    const int PSZ = (N + NPART - 1) / NPART;

    // workspace layout (4-byte elements)
    char* ws = (char*)d_ws;
    int*   deg_i   = (int*)ws;                         ws += (size_t)N * 4;
    int*   off     = (int*)ws;                         ws += (size_t)(N + 1) * 4;
    int*   cursor  = (int*)ws;                         ws += (size_t)(N + 1) * 4;
    int*   csr_src = (int*)ws;                         ws += (size_t)E * 4;
    float* msg1    = (float*)ws;                       ws += (size_t)N * 64 * 4;
    float* self1   = (float*)ws;                       ws += (size_t)N * 64 * 4;
    float* h1      = (float*)ws;                       ws += (size_t)N * 64 * 4;
    float* msg2    = (float*)ws;                       ws += (size_t)N * 32 * 4;
    float* self2   = (float*)ws;                       ws += (size_t)N * 32 * 4;
    float* h2      = (float*)ws;                       ws += (size_t)N * 32 * 4;

    float* pos = (float*)d_out;
    float* neg = pos + E;

    hipMemsetAsync(deg_i, 0, (size_t)N * sizeof(int), stream);

    // ---- CSR-by-dst build (XCD-partitioned) ----
    degree_part_kernel<<<512, 256, 0, stream>>>(dd_dst, deg_i, E, PSZ);
    scan_kernel<<<1, 1024, 0, stream>>>(deg_i, off, cursor, N);
    fill_part_kernel<<<512, 256, 0, stream>>>(dd_src, dd_dst, cursor, csr_src, E, PSZ);

    // ---- layer 1 (persistent 512-block GEMM: 2 blocks/CU at 64KB LDS) ----
    gemm2_kernel<128, 64><<<512, dim3(64, 4), 0, stream>>>(
        feat_drug, W1_dd, W1_self_drug, msg1, self1, N);
    gather_combine_kernel<64, true><<<(N + 3) / 4, 256, 0, stream>>>(
        msg1, csr_src, off, cursor, self1, b1, h1, N);

    // ---- layer 2 ----
    gemm2_kernel<64, 32><<<512, dim3(32, 8), 0, stream>>>(
        h1, W2_dd, W2_self_drug, msg2, self2, N);
    gather_combine_kernel<32, false><<<(N + 7) / 8, 256, 0, stream>>>(
        msg2, csr_src, off, cursor, self2, b2, h2, N);

    // ---- scorer (pos + neg fused) ----
    score2_kernel<<<4096, 256, 0, stream>>>(h2, dd_src, dd_dst, neg_src, neg_dst,
                                            w_rel, pos, neg, E, EN);
}

// Round 5
// 424.776 us; speedup vs baseline: 1.0828x; 1.0149x over previous
//
#include <hip/hip_runtime.h>

// ---------------------------------------------------------------------------
// Drug-path-only GNN (gene path is dead code w.r.t. outputs).
// Round 5: register-resident-weight GEMMs. Round-4 profile: gemm2<128,64>
// stuck at 118us, VALUBusy 8%, occupancy 10% -- per-FMA it issued 2 LDS
// reads + a broadcast global load (LDS/VMEM-issue-bound, 64KB LDS capped
// occupancy). Now lane n holds W[:,n] in 128 VGPRs (KOUT=64=wave width),
// a-row is readfirstlane-uniform scalar/broadcast, inner loop is pure FMA
// with 2 independent row-chains. No LDS at all.
// ---------------------------------------------------------------------------

#define NPART 8

// out[m][n] = sum_k A[m][k]*W[k][n]; KOUT==64; weights in VGPRs (col per lane)
template<int KIN>
__global__ __launch_bounds__(256) void gemm_reg_kernel(const float* __restrict__ A,
                                                       const float* __restrict__ W,
                                                       float* __restrict__ out, int M) {
    const int lane = threadIdx.x & 63;
    const int gwave = blockIdx.x * (blockDim.x >> 6) + (threadIdx.x >> 6);
    const int nwave = gridDim.x * (blockDim.x >> 6);
    float w[KIN];
#pragma unroll
    for (int k = 0; k < KIN; ++k) w[k] = W[k * 64 + lane];   // coalesced, once
    for (int m0 = gwave * 2; m0 < M; m0 += nwave * 2) {
        const int mu = __builtin_amdgcn_readfirstlane(m0);   // force uniform
        const float* a0 = A + (size_t)mu * KIN;
        const float* a1 = a0 + KIN;
        const bool two = (mu + 1) < M;
        float acc0 = 0.0f, acc1 = 0.0f;
#pragma unroll
        for (int k = 0; k < KIN; ++k) {
            const float av0 = a0[k];
            const float av1 = two ? a1[k] : 0.0f;
            acc0 = fmaf(av0, w[k], acc0);
            acc1 = fmaf(av1, w[k], acc1);
        }
        out[(size_t)mu * 64 + lane] = acc0;
        if (two) out[(size_t)(mu + 1) * 64 + lane] = acc1;
    }
}

// layer-2 pair: KIN=64, KOUT=32. Lanes 0..31 -> Wa cols, lanes 32..63 -> Wb.
__global__ __launch_bounds__(256) void gemm2_reg_kernel(const float* __restrict__ A,
                                                        const float* __restrict__ Wa,
                                                        const float* __restrict__ Wb,
                                                        float* __restrict__ out_a,
                                                        float* __restrict__ out_b, int M) {
    const int lane = threadIdx.x & 63;
    const int col = lane & 31;
    const float* Wm = (lane < 32) ? Wa : Wb;
    float* om = (lane < 32) ? out_a : out_b;
    const int gwave = blockIdx.x * (blockDim.x >> 6) + (threadIdx.x >> 6);
    const int nwave = gridDim.x * (blockDim.x >> 6);
    float w[64];
#pragma unroll
    for (int k = 0; k < 64; ++k) w[k] = Wm[k * 32 + col];
    for (int m0 = gwave * 2; m0 < M; m0 += nwave * 2) {
        const int mu = __builtin_amdgcn_readfirstlane(m0);
        const float* a0 = A + (size_t)mu * 64;
        const float* a1 = a0 + 64;
        const bool two = (mu + 1) < M;
        float acc0 = 0.0f, acc1 = 0.0f;
#pragma unroll
        for (int k = 0; k < 64; ++k) {
            const float av0 = a0[k];
            const float av1 = two ? a1[k] : 0.0f;
            acc0 = fmaf(av0, w[k], acc0);
            acc1 = fmaf(av1, w[k], acc1);
        }
        om[(size_t)mu * 32 + col] = acc0;
        if (two) om[(size_t)(mu + 1) * 32 + col] = acc1;
    }
}

// 8-way node-range-partitioned degree histogram; partition = blockIdx & 7.
__global__ __launch_bounds__(256) void degree_part_kernel(const int* __restrict__ dst,
                                                          int* __restrict__ deg,
                                                          int E, int psz) {
    const int part = blockIdx.x & (NPART - 1);
    const int lo = part * psz, hi = lo + psz;
    const int bpp = gridDim.x >> 3;
    const int bip = blockIdx.x >> 3;
    const int stride = bpp * 256;
    for (int e = bip * 256 + threadIdx.x; e < E; e += stride) {
        const int d = dst[e];
        if (d >= lo && d < hi) atomicAdd(&deg[d], 1);
    }
}

// single-block exclusive scan; writes off[0..N] and cursor[i]=off[i]
__global__ __launch_bounds__(1024) void scan_kernel(const int* __restrict__ deg,
                                                    int* __restrict__ off,
                                                    int* __restrict__ cursor, int N) {
    __shared__ int part[1024];
    const int t = threadIdx.x;
    const int per = (N + 1023) / 1024;
    const int beg = t * per;
    const int end = min(beg + per, N);
    int s = 0;
    for (int i = beg; i < end; ++i) s += deg[i];
    part[t] = s;
    __syncthreads();
    for (int d = 1; d < 1024; d <<= 1) {
        int v = (t >= d) ? part[t - d] : 0;
        __syncthreads();
        part[t] += v;
        __syncthreads();
    }
    int run = (t == 0) ? 0 : part[t - 1];
    for (int i = beg; i < end; ++i) { off[i] = run; cursor[i] = run; run += deg[i]; }
    if (t == 1023) off[N] = part[1023];
}

// 8-way partitioned bucket fill; after completion cursor[n] == segment end.
__global__ __launch_bounds__(256) void fill_part_kernel(const int* __restrict__ src,
                                                        const int* __restrict__ dst,
                                                        int* __restrict__ cursor,
                                                        int* __restrict__ csr_src,
                                                        int E, int psz) {
    const int part = blockIdx.x & (NPART - 1);
    const int lo = part * psz, hi = lo + psz;
    const int bpp = gridDim.x >> 3;
    const int bip = blockIdx.x >> 3;
    const int stride = bpp * 256;
    for (int e = bip * 256 + threadIdx.x; e < E; e += stride) {
        const int d = dst[e];
        const int s = src[e];
        if (d >= lo && d < hi) {
            const int p = atomicAdd(&cursor[d], 1);
            csr_src[p] = s;
        }
    }
}

// One W-lane group per dst node: register-accumulate, fused mean+self+bias(+relu)
template<int W, bool RELU>
__global__ __launch_bounds__(256) void gather_combine_kernel(
        const float* __restrict__ msg, const int* __restrict__ csr_src,
        const int* __restrict__ off, const int* __restrict__ endp,
        const float* __restrict__ selfb, const float* __restrict__ b,
        float* __restrict__ out, int N) {
    const int GRP = 256 / W;
    const int g = threadIdx.x / W;
    const int lane = threadIdx.x % W;
    const float bk = b[lane];
    for (int n = blockIdx.x * GRP + g; n < N; n += gridDim.x * GRP) {
        const int beg = off[n], end = endp[n];
        float acc = 0.0f;
        int i = beg;
        for (; i + 4 <= end; i += 4) {
            const int s0 = csr_src[i], s1 = csr_src[i + 1];
            const int s2 = csr_src[i + 2], s3 = csr_src[i + 3];
            const float v0 = msg[(size_t)s0 * W + lane];
            const float v1 = msg[(size_t)s1 * W + lane];
            const float v2 = msg[(size_t)s2 * W + lane];
            const float v3 = msg[(size_t)s3 * W + lane];
            acc += (v0 + v1) + (v2 + v3);
        }
        for (; i < end; ++i) acc += msg[(size_t)csr_src[i] * W + lane];
        const float d = (end > beg) ? (float)(end - beg) : 1.0f;
        float v = acc / d + selfb[(size_t)n * W + lane] + bk;
        if (RELU) v = fmaxf(v, 0.0f);
        out[(size_t)n * W + lane] = v;
    }
}

// fused pos+neg scorer: 8 lanes per edge, float4 slices of 32-wide h rows
__global__ __launch_bounds__(256) void score2_kernel(const float* __restrict__ h,
                                                     const int* __restrict__ sA,
                                                     const int* __restrict__ dA,
                                                     const int* __restrict__ sB,
                                                     const int* __restrict__ dB,
                                                     const float* __restrict__ wrel,
                                                     float* __restrict__ outA,
                                                     float* __restrict__ outB,
                                                     int EA, int EB) {
    const int lj = threadIdx.x & 7;
    const size_t grp = ((size_t)blockIdx.x * blockDim.x + threadIdx.x) >> 3;
    const size_t ngrp = ((size_t)gridDim.x * blockDim.x) >> 3;
    const float4 w = *(const float4*)(wrel + lj * 4);
    const size_t total = (size_t)EA + (size_t)EB;
    for (size_t e = grp; e < total; e += ngrp) {
        int s, d; float* o;
        if (e < (size_t)EA) { s = sA[e]; d = dA[e]; o = outA + e; }
        else { const size_t e2 = e - EA; s = sB[e2]; d = dB[e2]; o = outB + e2; }
        const float4 hs = *(const float4*)(h + (size_t)s * 32 + lj * 4);
        const float4 hd = *(const float4*)(h + (size_t)d * 32 + lj * 4);
        float p = hs.x * w.x * hd.x + hs.y * w.y * hd.y +
                  hs.z * w.z * hd.z + hs.w * w.w * hd.w;
        p += __shfl_xor(p, 1, 64);
        p += __shfl_xor(p, 2, 64);
        p += __shfl_xor(p, 4, 64);
        if (lj == 0) *o = p;
    }
}

extern "C" void kernel_launch(void* const* d_in, const int* in_sizes, int n_in,
                              void* d_out, int out_size, void* d_ws, size_t ws_size,
                              hipStream_t stream) {
    const float* feat_drug    = (const float*)d_in[0];
    const int*   dd_src       = (const int*)d_in[2];
    const int*   dd_dst       = (const int*)d_in[3];
    const int*   neg_src      = (const int*)d_in[8];
    const int*   neg_dst      = (const int*)d_in[9];
    const float* W1_dd        = (const float*)d_in[10];
    const float* W1_self_drug = (const float*)d_in[13];
    const float* b1           = (const float*)d_in[15];
    const float* W2_dd        = (const float*)d_in[16];
    const float* W2_self_drug = (const float*)d_in[19];
    const float* b2           = (const float*)d_in[21];
    const float* w_rel        = (const float*)d_in[22];

    const int N  = in_sizes[0] / 128;  // 20000 drugs
    const int E  = in_sizes[2];        // 1.5M dd edges
    const int EN = in_sizes[8];        // 1.5M neg edges
    const int PSZ = (N + NPART - 1) / NPART;

    // workspace layout (4-byte elements)
    char* ws = (char*)d_ws;
    int*   deg_i   = (int*)ws;                         ws += (size_t)N * 4;
    int*   off     = (int*)ws;                         ws += (size_t)(N + 1) * 4;
    int*   cursor  = (int*)ws;                         ws += (size_t)(N + 1) * 4;
    int*   csr_src = (int*)ws;                         ws += (size_t)E * 4;
    float* msg1    = (float*)ws;                       ws += (size_t)N * 64 * 4;
    float* self1   = (float*)ws;                       ws += (size_t)N * 64 * 4;
    float* h1      = (float*)ws;                       ws += (size_t)N * 64 * 4;
    float* msg2    = (float*)ws;                       ws += (size_t)N * 32 * 4;
    float* self2   = (float*)ws;                       ws += (size_t)N * 32 * 4;
    float* h2      = (float*)ws;                       ws += (size_t)N * 32 * 4;

    float* pos = (float*)d_out;
    float* neg = pos + E;

    hipMemsetAsync(deg_i, 0, (size_t)N * sizeof(int), stream);

    // ---- CSR-by-dst build (XCD-partitioned) ----
    degree_part_kernel<<<512, 256, 0, stream>>>(dd_dst, deg_i, E, PSZ);
    scan_kernel<<<1, 1024, 0, stream>>>(deg_i, off, cursor, N);
    fill_part_kernel<<<512, 256, 0, stream>>>(dd_src, dd_dst, cursor, csr_src, E, PSZ);

    // ---- layer 1: register-weight GEMMs (no LDS) ----
    gemm_reg_kernel<128><<<512, 256, 0, stream>>>(feat_drug, W1_dd, msg1, N);
    gemm_reg_kernel<128><<<512, 256, 0, stream>>>(feat_drug, W1_self_drug, self1, N);
    gather_combine_kernel<64, true><<<(N + 3) / 4, 256, 0, stream>>>(
        msg1, csr_src, off, cursor, self1, b1, h1, N);

    // ---- layer 2: fused dual-matrix register GEMM ----
    gemm2_reg_kernel<<<512, 256, 0, stream>>>(h1, W2_dd, W2_self_drug, msg2, self2, N);
    gather_combine_kernel<32, false><<<(N + 7) / 8, 256, 0, stream>>>(
        msg2, csr_src, off, cursor, self2, b2, h2, N);

    // ---- scorer (pos + neg fused) ----
    score2_kernel<<<4096, 256, 0, stream>>>(h2, dd_src, dd_dst, neg_src, neg_dst,
                                            w_rel, pos, neg, E, EN);
}